// Round 12
// baseline (287.133 us; speedup 1.0000x reference)
//
#include <hip/hip_runtime.h>

#define N_NODES 50000
#define E_EDGES 800000
#define E2      (2 * E_EDGES)
#define D_DIM   200
#define C_CLS   10
#define NB_BUCKET ((N_NODES + 255) / 256)   // 196 buckets, 256 rows each (r>>8)
#define BATCH     4096                       // edges per scatter block (32 KB LDS stash)
#define CAP       12288                      // stage slots/bucket: 8163 mean + 5sigma
                                             // + 391 blocks * 7 pad = 11350 < 12288
#define SENT      0xFFFFu                    // sentinel row id (rows < 50000)

static __device__ __forceinline__ unsigned short f2bf(float f) {
    unsigned u = __float_as_uint(f);
    return (unsigned short)((u + 0x7FFFu + ((u >> 16) & 1u)) >> 16);   // RNE
}
static __device__ __forceinline__ float bf_lo(unsigned u) {
    return __uint_as_float(u << 16);
}
static __device__ __forceinline__ float bf_hi(unsigned u) {
    return __uint_as_float(u & 0xFFFF0000u);
}

// ---------------------------------------------------------------------------
// W0 fp32 -> bf16 flat rows (400 B/row), 4 elems/thread. Block 0 zeroes bcur.
// ---------------------------------------------------------------------------
__global__ __launch_bounds__(256) void convert_w0_kernel(const float* __restrict__ W0,
                                                         unsigned short* __restrict__ W0h,
                                                         int* __restrict__ bcur) {
    if (blockIdx.x == 0 && threadIdx.x < NB_BUCKET) bcur[threadIdx.x] = 0;
    int i = (blockIdx.x * 256 + threadIdx.x) * 4;
    if (i >= N_NODES * D_DIM) return;
    float4 f = *(const float4*)(W0 + i);
    uint2 p;
    p.x = (unsigned)f2bf(f.x) | ((unsigned)f2bf(f.y) << 16);
    p.y = (unsigned)f2bf(f.z) | ((unsigned)f2bf(f.w) << 16);
    *(uint2*)(W0h + i) = p;
}

// ---------------------------------------------------------------------------
// Bucket scatter, LINE-ALIGNED runs: reservations rounded up to 8 records
// (64 B) so each block owns whole cache lines in the stage region — no
// cross-XCD partial-line sharing. Pad slots get sentinel records.
// ---------------------------------------------------------------------------
__global__ __launch_bounds__(256) void bucket_scatter_kernel(
        const int* __restrict__ rows0, const int* __restrict__ cols0,
        const float* __restrict__ vals0,
        const int* __restrict__ rows1, const int* __restrict__ cols1,
        const float* __restrict__ vals1,
        int* __restrict__ bcur,
        int2* __restrict__ stage) {
    __shared__ int cntL[NB_BUCKET];
    __shared__ int baseL[NB_BUCKET];
    __shared__ int offL[NB_BUCKET];
    __shared__ int2 recL[BATCH];            // 32 KB
    const int tid = threadIdx.x;
    const int e0 = blockIdx.x * BATCH;

    for (int b = tid; b < NB_BUCKET; b += 256) cntL[b] = 0;
    __syncthreads();

#pragma unroll
    for (int k = 0; k < BATCH / 256; ++k) {
        int idx = k * 256 + tid;
        int e = e0 + idx;
        if (e < E2) {
            int r, c;
            float v;
            if (e < E_EDGES) {
                r = rows0[e]; c = cols0[e]; v = vals0[e];
            } else {
                int e1 = e - E_EDGES;
                r = rows1[e1]; c = cols1[e1]; v = vals1[e1];
            }
            recL[idx] = make_int2((int)((unsigned)r | ((unsigned)c << 16)),
                                  __float_as_int(v));
            atomicAdd(&cntL[r >> 8], 1);
        }
    }
    __syncthreads();

    // Reserve line-aligned runs; sentinel-fill the pad tail of each run.
    for (int b = tid; b < NB_BUCKET; b += 256) {
        int c = cntL[b];
        int cpad = (c + 7) & ~7;
        int base = (cpad > 0) ? atomicAdd(&bcur[b], cpad) : 0;
        baseL[b] = base;
        offL[b] = 0;
        int2* bp = stage + (size_t)b * CAP;
        for (int s = base + c; s < base + cpad; ++s)
            bp[s] = make_int2((int)SENT, 0);
    }
    __syncthreads();

#pragma unroll
    for (int k = 0; k < BATCH / 256; ++k) {
        int idx = k * 256 + tid;
        int e = e0 + idx;
        if (e < E2) {
            int2 rec = recL[idx];
            int b = (int)(((unsigned)rec.x & 0xFFFFu) >> 8);
            int pos = baseL[b] + atomicAdd(&offL[b], 1);
            stage[(size_t)b * CAP + pos] = rec;
        }
    }
}

// ---------------------------------------------------------------------------
// Hist+scan (fused row_count + scan1): one block per bucket. LDS histogram of
// the bucket's 256 rows (skipping sentinels) -> block exclusive scan ->
// excl[row] (within-bucket offset) + bsum[b] (bucket's real record count).
// ---------------------------------------------------------------------------
__global__ __launch_bounds__(256) void hist_scan_kernel(const int* __restrict__ bcur,
                                                        const int2* __restrict__ stage,
                                                        int* __restrict__ excl,
                                                        int* __restrict__ bsum) {
    __shared__ int hist[256];
    __shared__ int ws4[4];
    const int b = blockIdx.x;
    const int tid = threadIdx.x;
    const int lane = tid & 63;
    const int w = tid >> 6;
    hist[tid] = 0;
    __syncthreads();

    const int n = bcur[b];                  // padded count <= CAP
    const int2* __restrict__ sp = stage + (size_t)b * CAP;
    for (int i = tid; i < n; i += 256) {
        unsigned u = (unsigned)sp[i].x;
        if ((u & 0xFFFFu) != SENT)
            atomicAdd(&hist[u & 255u], 1);
    }
    __syncthreads();

    int v = hist[tid];
    int orig = v;
#pragma unroll
    for (int off = 1; off < 64; off <<= 1) {
        int t = __shfl_up(v, off, 64);
        if (lane >= off) v += t;
    }
    if (lane == 63) ws4[w] = v;
    __syncthreads();
    if (tid == 0) {
        int s = 0;
#pragma unroll
        for (int k = 0; k < 4; ++k) { int t = ws4[k]; ws4[k] = s; s += t; }
    }
    __syncthreads();
    v += ws4[w];

    const int row = (b << 8) + tid;
    if (row < N_NODES) excl[row] = v - orig;   // exclusive within bucket
    if (tid == 255) bsum[b] = v;               // total real records
}

// ---------------------------------------------------------------------------
// scan2 (proven r4..r11): exclusive scan of 196 bucket totals, in place;
// writes row_ptr[N_NODES] = E2.
// ---------------------------------------------------------------------------
__global__ __launch_bounds__(64) void scan2_kernel(int* __restrict__ bsum,
                                                   int* __restrict__ row_ptr) {
    const int lane = threadIdx.x;
    int carry = 0;
    for (int base = 0; base < NB_BUCKET; base += 64) {
        int idx = base + lane;
        int v = (idx < NB_BUCKET) ? bsum[idx] : 0;
        int orig = v;
#pragma unroll
        for (int off = 1; off < 64; off <<= 1) {
            int t = __shfl_up(v, off, 64);
            if (lane >= off) v += t;
        }
        int chunk_total = __shfl(v, 63, 64);
        int ex = v - orig + carry;
        if (idx < NB_BUCKET) bsum[idx] = ex;
        carry += chunk_total;
    }
    if (lane == 0) row_ptr[N_NODES] = carry;
}

// ---------------------------------------------------------------------------
// Sort+place (fused scan3 + bucket_sort): computes row_ptr[row] =
// bsum[b] + excl[row] inline, then places records (skipping sentinels) into
// final CSR order as cv4[e] = (col<<16) | bf16(val).
// ---------------------------------------------------------------------------
__global__ __launch_bounds__(256) void sort_place_kernel(const int* __restrict__ excl,
                                                         const int* __restrict__ bsum,
                                                         const int* __restrict__ bcur,
                                                         const int2* __restrict__ stage,
                                                         int* __restrict__ row_ptr,
                                                         unsigned* __restrict__ cv4) {
    __shared__ int lcur[256];
    const int b = blockIdx.x;
    const int tid = threadIdx.x;
    const int base = bsum[b];
    const int row = (b << 8) + tid;
    int ex = base + ((row < N_NODES) ? excl[row] : 0);
    if (row < N_NODES) row_ptr[row] = ex;
    lcur[tid] = ex;
    __syncthreads();

    const int n = bcur[b];
    const int2* __restrict__ sp = stage + (size_t)b * CAP;
    for (int i = tid; i < n; i += 256) {
        int2 rec = sp[i];
        unsigned u = (unsigned)rec.x;
        if ((u & 0xFFFFu) == SENT) continue;
        int pos = atomicAdd(&lcur[u & 255u], 1);
        cv4[pos] = (u & 0xFFFF0000u) | (unsigned)f2bf(__int_as_float(rec.y));
    }
}

// ---------------------------------------------------------------------------
// Fused layer 0 (r9/r11-proven unroll-8, cv4): per node n,
//   t = relu( sum_e v_e * W0h[c_e,:] + s0 * W0h[n,:] ); g[n,:] = t @ W1
// ---------------------------------------------------------------------------
__global__ __launch_bounds__(256) void spmm_layer0_fused_kernel(
        const int*  __restrict__ row_ptr,
        const unsigned* __restrict__ cv4,
        const unsigned short* __restrict__ W0h,
        const float* __restrict__ W1,
        const float* __restrict__ eps0,
        float* __restrict__ g) {
    __shared__ float W1s[D_DIM * C_CLS];
    for (int i = threadIdx.x; i < D_DIM * C_CLS; i += blockDim.x) W1s[i] = W1[i];
    __syncthreads();

    const int lane = threadIdx.x & 63;
    const int n = __builtin_amdgcn_readfirstlane(blockIdx.x * 4 + (threadIdx.x >> 6));
    if (n >= N_NODES) return;
    const float s0 = 0.1f * (1.0f + eps0[0]);
    const bool act = (lane < 50);
    const uint2* __restrict__ F = (const uint2*)W0h;

    const int beg  = row_ptr[n];
    const int endp = row_ptr[n + 1];
    float a0 = 0.f, a1 = 0.f, a2 = 0.f, a3 = 0.f;

    int e = beg;
    for (; e + 8 <= endp; e += 8) {
        unsigned w0 = cv4[e],     w1 = cv4[e + 1], w2 = cv4[e + 2], w3 = cv4[e + 3];
        unsigned w4 = cv4[e + 4], w5 = cv4[e + 5], w6 = cv4[e + 6], w7 = cv4[e + 7];
        if (act) {
            uint2 u0 = F[(size_t)(w0 >> 16) * 50 + lane];
            uint2 u1 = F[(size_t)(w1 >> 16) * 50 + lane];
            uint2 u2 = F[(size_t)(w2 >> 16) * 50 + lane];
            uint2 u3 = F[(size_t)(w3 >> 16) * 50 + lane];
            uint2 u4 = F[(size_t)(w4 >> 16) * 50 + lane];
            uint2 u5 = F[(size_t)(w5 >> 16) * 50 + lane];
            uint2 u6 = F[(size_t)(w6 >> 16) * 50 + lane];
            uint2 u7 = F[(size_t)(w7 >> 16) * 50 + lane];
            float v0 = __uint_as_float(w0 << 16), v1 = __uint_as_float(w1 << 16);
            float v2 = __uint_as_float(w2 << 16), v3 = __uint_as_float(w3 << 16);
            float v4 = __uint_as_float(w4 << 16), v5 = __uint_as_float(w5 << 16);
            float v6 = __uint_as_float(w6 << 16), v7 = __uint_as_float(w7 << 16);
            a0 += v0 * bf_lo(u0.x) + v1 * bf_lo(u1.x) + v2 * bf_lo(u2.x) + v3 * bf_lo(u3.x)
                + v4 * bf_lo(u4.x) + v5 * bf_lo(u5.x) + v6 * bf_lo(u6.x) + v7 * bf_lo(u7.x);
            a1 += v0 * bf_hi(u0.x) + v1 * bf_hi(u1.x) + v2 * bf_hi(u2.x) + v3 * bf_hi(u3.x)
                + v4 * bf_hi(u4.x) + v5 * bf_hi(u5.x) + v6 * bf_hi(u6.x) + v7 * bf_hi(u7.x);
            a2 += v0 * bf_lo(u0.y) + v1 * bf_lo(u1.y) + v2 * bf_lo(u2.y) + v3 * bf_lo(u3.y)
                + v4 * bf_lo(u4.y) + v5 * bf_lo(u5.y) + v6 * bf_lo(u6.y) + v7 * bf_lo(u7.y);
            a3 += v0 * bf_hi(u0.y) + v1 * bf_hi(u1.y) + v2 * bf_hi(u2.y) + v3 * bf_hi(u3.y)
                + v4 * bf_hi(u4.y) + v5 * bf_hi(u5.y) + v6 * bf_hi(u6.y) + v7 * bf_hi(u7.y);
        }
    }
    for (; e + 4 <= endp; e += 4) {
        unsigned w0 = cv4[e], w1 = cv4[e + 1], w2 = cv4[e + 2], w3 = cv4[e + 3];
        if (act) {
            uint2 u0 = F[(size_t)(w0 >> 16) * 50 + lane];
            uint2 u1 = F[(size_t)(w1 >> 16) * 50 + lane];
            uint2 u2 = F[(size_t)(w2 >> 16) * 50 + lane];
            uint2 u3 = F[(size_t)(w3 >> 16) * 50 + lane];
            float v0 = __uint_as_float(w0 << 16), v1 = __uint_as_float(w1 << 16);
            float v2 = __uint_as_float(w2 << 16), v3 = __uint_as_float(w3 << 16);
            a0 += v0 * bf_lo(u0.x) + v1 * bf_lo(u1.x) + v2 * bf_lo(u2.x) + v3 * bf_lo(u3.x);
            a1 += v0 * bf_hi(u0.x) + v1 * bf_hi(u1.x) + v2 * bf_hi(u2.x) + v3 * bf_hi(u3.x);
            a2 += v0 * bf_lo(u0.y) + v1 * bf_lo(u1.y) + v2 * bf_lo(u2.y) + v3 * bf_lo(u3.y);
            a3 += v0 * bf_hi(u0.y) + v1 * bf_hi(u1.y) + v2 * bf_hi(u2.y) + v3 * bf_hi(u3.y);
        }
    }
    for (; e < endp; ++e) {
        unsigned w = cv4[e];
        if (act) {
            uint2 u = F[(size_t)(w >> 16) * 50 + lane];
            float v = __uint_as_float(w << 16);
            a0 += v * bf_lo(u.x);
            a1 += v * bf_hi(u.x);
            a2 += v * bf_lo(u.y);
            a3 += v * bf_hi(u.y);
        }
    }

    float o[C_CLS];
#pragma unroll
    for (int k = 0; k < C_CLS; ++k) o[k] = 0.f;

    if (act) {
        uint2 w = F[(size_t)n * 50 + lane];
        a0 = fmaxf(a0 + s0 * bf_lo(w.x), 0.f);
        a1 = fmaxf(a1 + s0 * bf_hi(w.x), 0.f);
        a2 = fmaxf(a2 + s0 * bf_lo(w.y), 0.f);
        a3 = fmaxf(a3 + s0 * bf_hi(w.y), 0.f);
        const int d = lane * 4;
#pragma unroll
        for (int k = 0; k < C_CLS; ++k) {
            o[k] = a0 * W1s[(d + 0) * C_CLS + k]
                 + a1 * W1s[(d + 1) * C_CLS + k]
                 + a2 * W1s[(d + 2) * C_CLS + k]
                 + a3 * W1s[(d + 3) * C_CLS + k];
        }
    }

#pragma unroll
    for (int k = 0; k < C_CLS; ++k) {
        for (int off = 32; off > 0; off >>= 1)
            o[k] += __shfl_xor(o[k], off, 64);
    }

    if (lane == 0) {
        float* gp = g + (size_t)n * C_CLS;
#pragma unroll
        for (int k = 0; k < C_CLS; ++k) gp[k] = o[k];
    }
}

// ---------------------------------------------------------------------------
// Light layer 1 (r10/r11-proven cv4 variant):
//   out[n,:] = sum_e v_e * g[c_e,:] + s1 * g[n,:]
// ---------------------------------------------------------------------------
__global__ __launch_bounds__(256) void spmm_layer1_light_kernel(
        const int*  __restrict__ row_ptr,
        const unsigned* __restrict__ cv4,
        const float* __restrict__ g,
        const float* __restrict__ eps1,
        float* __restrict__ out) {
    const int lane = threadIdx.x & 63;
    const int n = __builtin_amdgcn_readfirstlane(blockIdx.x * 4 + (threadIdx.x >> 6));
    if (n >= N_NODES) return;
    const int grp = lane / 10;          // 0..5 active, 6 for lanes 60-63 (idle)
    const int d   = lane - grp * 10;    // 0..9
    const float s1 = 0.1f * (1.0f + eps1[0]);

    const int beg  = row_ptr[n];
    const int endp = row_ptr[n + 1];
    float acc = 0.f;

    for (int base = beg; base < endp; base += 6) {
        int e = base + grp;
        if (grp < 6 && e < endp) {
            unsigned p = cv4[e];
            float vf = __uint_as_float(p << 16);
            acc += vf * g[(size_t)(p >> 16) * C_CLS + d];
        }
    }

    float t;
    t = __shfl(acc, lane + 10, 64); if (lane < 50) acc += t;
    t = __shfl(acc, lane + 20, 64); if (lane < 30) acc += t;
    t = __shfl(acc, lane + 40, 64); if (lane < 10) acc += t;

    if (lane < 10) {
        out[(size_t)n * C_CLS + d] = acc + s1 * g[(size_t)n * C_CLS + d];
    }
}

// ---------------------------------------------------------------------------
extern "C" void kernel_launch(void* const* d_in, const int* in_sizes, int n_in,
                              void* d_out, int out_size, void* d_ws, size_t ws_size,
                              hipStream_t stream) {
    // setup_inputs order: x, rows0, cols0, vals0, rows1, cols1, vals1, W0, W1, eps0, eps1
    const int*   rows0 = (const int*)d_in[1];
    const int*   cols0 = (const int*)d_in[2];
    const float* vals0 = (const float*)d_in[3];
    const int*   rows1 = (const int*)d_in[4];
    const int*   cols1 = (const int*)d_in[5];
    const float* vals1 = (const float*)d_in[6];
    const float* W0    = (const float*)d_in[7];
    const float* W1    = (const float*)d_in[8];
    const float* eps0  = (const float*)d_in[9];
    const float* eps1  = (const float*)d_in[10];
    float* out = (float*)d_out;

    char* ws = (char*)d_ws;
    size_t off = 0;
    auto alloc = [&](size_t bytes) {
        void* p = ws + off;
        off += (bytes + 255) & ~(size_t)255;
        return p;
    };
    unsigned short* W0h = (unsigned short*)alloc((size_t)N_NODES * D_DIM * 2);  // 20 MB
    float* g      = (float*)alloc((size_t)N_NODES * C_CLS * 4);                 // 2 MB
    int* excl     = (int*)alloc((size_t)N_NODES * 4);
    int* bsum     = (int*)alloc((size_t)NB_BUCKET * 4);
    int* row_ptr  = (int*)alloc((size_t)(N_NODES + 1) * 4);
    int* bcur     = (int*)alloc((size_t)NB_BUCKET * 4);
    unsigned* cv4 = (unsigned*)alloc((size_t)E2 * 4);                           // 6.4 MB
    int2* stage   = (int2*)alloc((size_t)NB_BUCKET * CAP * 8);                  // 19.3 MB
    (void)ws_size;

    convert_w0_kernel<<<(N_NODES * D_DIM / 4 + 255) / 256, 256, 0, stream>>>(W0, W0h, bcur);
    bucket_scatter_kernel<<<(E2 + BATCH - 1) / BATCH, 256, 0, stream>>>(
        rows0, cols0, vals0, rows1, cols1, vals1, bcur, stage);
    hist_scan_kernel<<<NB_BUCKET, 256, 0, stream>>>(bcur, stage, excl, bsum);
    scan2_kernel<<<1, 64, 0, stream>>>(bsum, row_ptr);
    sort_place_kernel<<<NB_BUCKET, 256, 0, stream>>>(excl, bsum, bcur, stage, row_ptr, cv4);

    const int spmm_grid = (N_NODES + 3) / 4;   // 4 waves/block, 1 wave per node
    spmm_layer0_fused_kernel<<<spmm_grid, 256, 0, stream>>>(
        row_ptr, cv4, W0h, W1, eps0, g);
    spmm_layer1_light_kernel<<<spmm_grid, 256, 0, stream>>>(
        row_ptr, cv4, g, eps1, out);
}

// Round 13
// 273.843 us; speedup vs baseline: 1.0485x; 1.0485x over previous
//
#include <hip/hip_runtime.h>

#define N_NODES 50000
#define E_EDGES 800000
#define E2      (2 * E_EDGES)
#define D_DIM   200
#define C_CLS   10
#define NB_BUCKET 196                        // buckets of 256 rows (r>>8)
#define BATCH     4096                       // edges per scatter block
#define NB_SCATTER ((E2 + BATCH - 1) / BATCH)        // 391
#define NB_CONV    ((N_NODES * D_DIM / 4 + 255) / 256) // 9766
#define CAP       12288                      // stage slots/bucket (mean 8163, >45 sigma)

static __device__ __forceinline__ unsigned f2bf(float f) {
    unsigned u = __float_as_uint(f);
    return (u + 0x7FFFu + ((u >> 16) & 1u)) >> 16;     // RNE, low 16 bits
}
static __device__ __forceinline__ float bf_lo(unsigned u) {
    return __uint_as_float(u << 16);
}
static __device__ __forceinline__ float bf_hi(unsigned u) {
    return __uint_as_float(u & 0xFFFF0000u);
}

// ---------------------------------------------------------------------------
// Fused convert + scatter. Blocks [0, NB_SCATTER): r11-proven bucket scatter
// (LDS stash, per-bucket contiguous runs, ~77K global atomics). Blocks
// [NB_SCATTER, +NB_CONV): W0 fp32 -> bf16 stream (independent arrays).
// bcur and the ticket counter are zeroed by hipMemsetAsync beforehand.
// ---------------------------------------------------------------------------
__global__ __launch_bounds__(256) void convert_scatter_kernel(
        const float* __restrict__ W0, unsigned short* __restrict__ W0h,
        const int* __restrict__ rows0, const int* __restrict__ cols0,
        const float* __restrict__ vals0,
        const int* __restrict__ rows1, const int* __restrict__ cols1,
        const float* __restrict__ vals1,
        int* __restrict__ bcur,
        int2* __restrict__ stage) {
    __shared__ int cntL[NB_BUCKET];
    __shared__ int baseL[NB_BUCKET];
    __shared__ int offL[NB_BUCKET];
    __shared__ int2 recL[BATCH];            // 32 KB

    if (blockIdx.x >= NB_SCATTER) {
        // ---- convert path (streaming, no LDS use) ----
        int i = ((blockIdx.x - NB_SCATTER) * 256 + threadIdx.x) * 4;
        if (i < N_NODES * D_DIM) {
            float4 f = *(const float4*)(W0 + i);
            uint2 p;
            p.x = f2bf(f.x) | (f2bf(f.y) << 16);
            p.y = f2bf(f.z) | (f2bf(f.w) << 16);
            *(uint2*)(W0h + i) = p;
        }
        return;
    }

    // ---- scatter path (r11-proven body) ----
    const int tid = threadIdx.x;
    const int e0 = blockIdx.x * BATCH;

    for (int b = tid; b < NB_BUCKET; b += 256) cntL[b] = 0;
    __syncthreads();

#pragma unroll
    for (int k = 0; k < BATCH / 256; ++k) {
        int idx = k * 256 + tid;
        int e = e0 + idx;
        if (e < E2) {
            int r, c;
            float v;
            if (e < E_EDGES) {
                r = rows0[e]; c = cols0[e]; v = vals0[e];
            } else {
                int e1 = e - E_EDGES;
                r = rows1[e1]; c = cols1[e1]; v = vals1[e1];
            }
            recL[idx] = make_int2((int)((unsigned)r | ((unsigned)c << 16)),
                                  __float_as_int(v));
            atomicAdd(&cntL[r >> 8], 1);
        }
    }
    __syncthreads();

    for (int b = tid; b < NB_BUCKET; b += 256) {
        int c = cntL[b];
        baseL[b] = (c > 0) ? atomicAdd(&bcur[b], c) : 0;
        offL[b] = 0;
    }
    __syncthreads();

#pragma unroll
    for (int k = 0; k < BATCH / 256; ++k) {
        int idx = k * 256 + tid;
        int e = e0 + idx;
        if (e < E2) {
            int2 rec = recL[idx];
            int b = (int)(((unsigned)rec.x & 0xFFFFu) >> 8);
            int pos = baseL[b] + atomicAdd(&offL[b], 1);
            stage[(size_t)b * CAP + pos] = rec;
        }
    }
}

// ---------------------------------------------------------------------------
// Build CSR in ONE kernel (replaces hist_scan + scan2 + sort_place):
// per bucket: LDS row histogram -> block exclusive scan -> reserve cv4 span
// via global ticket atomic -> rowseg[row] = (start, count) -> place records.
// Bucket bases are arrival-ordered (non-deterministic layout) but rowseg and
// cv4 are mutually consistent; per-row record order is preserved, so the
// fp32 per-row sums are unchanged.
// ---------------------------------------------------------------------------
__global__ __launch_bounds__(256) void build_csr_kernel(
        const int* __restrict__ bcur,
        const int2* __restrict__ stage,
        int* __restrict__ ticket,
        int2* __restrict__ rowseg,
        unsigned* __restrict__ cv4) {
    __shared__ int hist[256];
    __shared__ int lcur[256];
    __shared__ int ws4[4];
    __shared__ int sbase;
    const int b = blockIdx.x;
    const int tid = threadIdx.x;
    const int lane = tid & 63;
    const int w = tid >> 6;
    hist[tid] = 0;
    __syncthreads();

    const int n = bcur[b];
    const int2* __restrict__ sp = stage + (size_t)b * CAP;
    for (int i = tid; i < n; i += 256)
        atomicAdd(&hist[(unsigned)sp[i].x & 255u], 1);
    __syncthreads();

    // Block inclusive scan of hist.
    int v = hist[tid];
    const int orig = v;
#pragma unroll
    for (int off = 1; off < 64; off <<= 1) {
        int t = __shfl_up(v, off, 64);
        if (lane >= off) v += t;
    }
    if (lane == 63) ws4[w] = v;
    __syncthreads();
    if (tid == 0) {
        int s = 0;
#pragma unroll
        for (int k = 0; k < 4; ++k) { int t = ws4[k]; ws4[k] = s; s += t; }
    }
    __syncthreads();
    v += ws4[w];                              // inclusive over 256 rows

    if (tid == 255) sbase = atomicAdd(ticket, v);   // reserve [sbase, sbase+total)
    __syncthreads();

    const int start = sbase + v - orig;       // exclusive + base
    const int row = (b << 8) + tid;
    if (row < N_NODES) rowseg[row] = make_int2(start, orig);
    lcur[tid] = start;
    __syncthreads();

    for (int i = tid; i < n; i += 256) {
        int2 rec = sp[i];
        unsigned u = (unsigned)rec.x;
        int pos = atomicAdd(&lcur[u & 255u], 1);
        cv4[pos] = (u & 0xFFFF0000u) | f2bf(__int_as_float(rec.y));
    }
}

// ---------------------------------------------------------------------------
// Fused layer 0 (r9/r11-proven unroll-8, rowseg variant): per node n,
//   t = relu( sum_e v_e * W0h[c_e,:] + s0 * W0h[n,:] ); g[n,:] = t @ W1
// ---------------------------------------------------------------------------
__global__ __launch_bounds__(256) void spmm_layer0_fused_kernel(
        const int2* __restrict__ rowseg,
        const unsigned* __restrict__ cv4,
        const unsigned short* __restrict__ W0h,
        const float* __restrict__ W1,
        const float* __restrict__ eps0,
        float* __restrict__ g) {
    __shared__ float W1s[D_DIM * C_CLS];
    for (int i = threadIdx.x; i < D_DIM * C_CLS; i += blockDim.x) W1s[i] = W1[i];
    __syncthreads();

    const int lane = threadIdx.x & 63;
    const int n = __builtin_amdgcn_readfirstlane(blockIdx.x * 4 + (threadIdx.x >> 6));
    if (n >= N_NODES) return;
    const float s0 = 0.1f * (1.0f + eps0[0]);
    const bool act = (lane < 50);
    const uint2* __restrict__ F = (const uint2*)W0h;

    const int2 seg = rowseg[n];
    const int beg  = seg.x;
    const int endp = seg.x + seg.y;
    float a0 = 0.f, a1 = 0.f, a2 = 0.f, a3 = 0.f;

    int e = beg;
    for (; e + 8 <= endp; e += 8) {
        unsigned w0 = cv4[e],     w1 = cv4[e + 1], w2 = cv4[e + 2], w3 = cv4[e + 3];
        unsigned w4 = cv4[e + 4], w5 = cv4[e + 5], w6 = cv4[e + 6], w7 = cv4[e + 7];
        if (act) {
            uint2 u0 = F[(size_t)(w0 >> 16) * 50 + lane];
            uint2 u1 = F[(size_t)(w1 >> 16) * 50 + lane];
            uint2 u2 = F[(size_t)(w2 >> 16) * 50 + lane];
            uint2 u3 = F[(size_t)(w3 >> 16) * 50 + lane];
            uint2 u4 = F[(size_t)(w4 >> 16) * 50 + lane];
            uint2 u5 = F[(size_t)(w5 >> 16) * 50 + lane];
            uint2 u6 = F[(size_t)(w6 >> 16) * 50 + lane];
            uint2 u7 = F[(size_t)(w7 >> 16) * 50 + lane];
            float v0 = __uint_as_float(w0 << 16), v1 = __uint_as_float(w1 << 16);
            float v2 = __uint_as_float(w2 << 16), v3 = __uint_as_float(w3 << 16);
            float v4 = __uint_as_float(w4 << 16), v5 = __uint_as_float(w5 << 16);
            float v6 = __uint_as_float(w6 << 16), v7 = __uint_as_float(w7 << 16);
            a0 += v0 * bf_lo(u0.x) + v1 * bf_lo(u1.x) + v2 * bf_lo(u2.x) + v3 * bf_lo(u3.x)
                + v4 * bf_lo(u4.x) + v5 * bf_lo(u5.x) + v6 * bf_lo(u6.x) + v7 * bf_lo(u7.x);
            a1 += v0 * bf_hi(u0.x) + v1 * bf_hi(u1.x) + v2 * bf_hi(u2.x) + v3 * bf_hi(u3.x)
                + v4 * bf_hi(u4.x) + v5 * bf_hi(u5.x) + v6 * bf_hi(u6.x) + v7 * bf_hi(u7.x);
            a2 += v0 * bf_lo(u0.y) + v1 * bf_lo(u1.y) + v2 * bf_lo(u2.y) + v3 * bf_lo(u3.y)
                + v4 * bf_lo(u4.y) + v5 * bf_lo(u5.y) + v6 * bf_lo(u6.y) + v7 * bf_lo(u7.y);
            a3 += v0 * bf_hi(u0.y) + v1 * bf_hi(u1.y) + v2 * bf_hi(u2.y) + v3 * bf_hi(u3.y)
                + v4 * bf_hi(u4.y) + v5 * bf_hi(u5.y) + v6 * bf_hi(u6.y) + v7 * bf_hi(u7.y);
        }
    }
    for (; e + 4 <= endp; e += 4) {
        unsigned w0 = cv4[e], w1 = cv4[e + 1], w2 = cv4[e + 2], w3 = cv4[e + 3];
        if (act) {
            uint2 u0 = F[(size_t)(w0 >> 16) * 50 + lane];
            uint2 u1 = F[(size_t)(w1 >> 16) * 50 + lane];
            uint2 u2 = F[(size_t)(w2 >> 16) * 50 + lane];
            uint2 u3 = F[(size_t)(w3 >> 16) * 50 + lane];
            float v0 = __uint_as_float(w0 << 16), v1 = __uint_as_float(w1 << 16);
            float v2 = __uint_as_float(w2 << 16), v3 = __uint_as_float(w3 << 16);
            a0 += v0 * bf_lo(u0.x) + v1 * bf_lo(u1.x) + v2 * bf_lo(u2.x) + v3 * bf_lo(u3.x);
            a1 += v0 * bf_hi(u0.x) + v1 * bf_hi(u1.x) + v2 * bf_hi(u2.x) + v3 * bf_hi(u3.x);
            a2 += v0 * bf_lo(u0.y) + v1 * bf_lo(u1.y) + v2 * bf_lo(u2.y) + v3 * bf_lo(u3.y);
            a3 += v0 * bf_hi(u0.y) + v1 * bf_hi(u1.y) + v2 * bf_hi(u2.y) + v3 * bf_hi(u3.y);
        }
    }
    for (; e < endp; ++e) {
        unsigned w = cv4[e];
        if (act) {
            uint2 u = F[(size_t)(w >> 16) * 50 + lane];
            float v = __uint_as_float(w << 16);
            a0 += v * bf_lo(u.x);
            a1 += v * bf_hi(u.x);
            a2 += v * bf_lo(u.y);
            a3 += v * bf_hi(u.y);
        }
    }

    float o[C_CLS];
#pragma unroll
    for (int k = 0; k < C_CLS; ++k) o[k] = 0.f;

    if (act) {
        uint2 w = F[(size_t)n * 50 + lane];
        a0 = fmaxf(a0 + s0 * bf_lo(w.x), 0.f);
        a1 = fmaxf(a1 + s0 * bf_hi(w.x), 0.f);
        a2 = fmaxf(a2 + s0 * bf_lo(w.y), 0.f);
        a3 = fmaxf(a3 + s0 * bf_hi(w.y), 0.f);
        const int d = lane * 4;
#pragma unroll
        for (int k = 0; k < C_CLS; ++k) {
            o[k] = a0 * W1s[(d + 0) * C_CLS + k]
                 + a1 * W1s[(d + 1) * C_CLS + k]
                 + a2 * W1s[(d + 2) * C_CLS + k]
                 + a3 * W1s[(d + 3) * C_CLS + k];
        }
    }

#pragma unroll
    for (int k = 0; k < C_CLS; ++k) {
        for (int off = 32; off > 0; off >>= 1)
            o[k] += __shfl_xor(o[k], off, 64);
    }

    if (lane == 0) {
        float* gp = g + (size_t)n * C_CLS;
#pragma unroll
        for (int k = 0; k < C_CLS; ++k) gp[k] = o[k];
    }
}

// ---------------------------------------------------------------------------
// Light layer 1 (r10/r11-proven, rowseg + unroll-2):
//   out[n,:] = sum_e v_e * g[c_e,:] + s1 * g[n,:]
// ---------------------------------------------------------------------------
__global__ __launch_bounds__(256) void spmm_layer1_light_kernel(
        const int2* __restrict__ rowseg,
        const unsigned* __restrict__ cv4,
        const float* __restrict__ g,
        const float* __restrict__ eps1,
        float* __restrict__ out) {
    const int lane = threadIdx.x & 63;
    const int n = __builtin_amdgcn_readfirstlane(blockIdx.x * 4 + (threadIdx.x >> 6));
    if (n >= N_NODES) return;
    const int grp = lane / 10;          // 0..5 active, 6 for lanes 60-63 (idle)
    const int d   = lane - grp * 10;    // 0..9
    const float s1 = 0.1f * (1.0f + eps1[0]);

    const int2 seg = rowseg[n];
    const int beg  = seg.x;
    const int endp = seg.x + seg.y;
    float acc = 0.f;

    for (int base = beg; base < endp; base += 12) {
        if (grp < 6) {
            int ea = base + grp;
            int eb = base + 6 + grp;
            unsigned pa = (ea < endp) ? cv4[ea] : 0u;
            unsigned pb = (eb < endp) ? cv4[eb] : 0u;
            if (ea < endp)
                acc += __uint_as_float(pa << 16) * g[(size_t)(pa >> 16) * C_CLS + d];
            if (eb < endp)
                acc += __uint_as_float(pb << 16) * g[(size_t)(pb >> 16) * C_CLS + d];
        }
    }

    float t;
    t = __shfl(acc, lane + 10, 64); if (lane < 50) acc += t;
    t = __shfl(acc, lane + 20, 64); if (lane < 30) acc += t;
    t = __shfl(acc, lane + 40, 64); if (lane < 10) acc += t;

    if (lane < 10) {
        out[(size_t)n * C_CLS + d] = acc + s1 * g[(size_t)n * C_CLS + d];
    }
}

// ---------------------------------------------------------------------------
extern "C" void kernel_launch(void* const* d_in, const int* in_sizes, int n_in,
                              void* d_out, int out_size, void* d_ws, size_t ws_size,
                              hipStream_t stream) {
    // setup_inputs order: x, rows0, cols0, vals0, rows1, cols1, vals1, W0, W1, eps0, eps1
    const int*   rows0 = (const int*)d_in[1];
    const int*   cols0 = (const int*)d_in[2];
    const float* vals0 = (const float*)d_in[3];
    const int*   rows1 = (const int*)d_in[4];
    const int*   cols1 = (const int*)d_in[5];
    const float* vals1 = (const float*)d_in[6];
    const float* W0    = (const float*)d_in[7];
    const float* W1    = (const float*)d_in[8];
    const float* eps0  = (const float*)d_in[9];
    const float* eps1  = (const float*)d_in[10];
    float* out = (float*)d_out;

    char* ws = (char*)d_ws;
    size_t off = 0;
    auto alloc = [&](size_t bytes) {
        void* p = ws + off;
        off += (bytes + 255) & ~(size_t)255;
        return p;
    };
    unsigned short* W0h = (unsigned short*)alloc((size_t)N_NODES * D_DIM * 2);  // 20 MB
    float* g      = (float*)alloc((size_t)N_NODES * C_CLS * 4);                 // 2 MB
    int2* rowseg  = (int2*)alloc((size_t)N_NODES * 8);                          // 400 KB
    int* bcur     = (int*)alloc((size_t)(NB_BUCKET + 1) * 4);                   // +ticket
    unsigned* cv4 = (unsigned*)alloc((size_t)E2 * 4);                           // 6.4 MB
    int2* stage   = (int2*)alloc((size_t)NB_BUCKET * CAP * 8);                  // 19.3 MB
    int* ticket   = bcur + NB_BUCKET;
    (void)ws_size;

    hipMemsetAsync(bcur, 0, (size_t)(NB_BUCKET + 1) * 4, stream);
    convert_scatter_kernel<<<NB_SCATTER + NB_CONV, 256, 0, stream>>>(
        W0, W0h, rows0, cols0, vals0, rows1, cols1, vals1, bcur, stage);
    build_csr_kernel<<<NB_BUCKET, 256, 0, stream>>>(bcur, stage, ticket, rowseg, cv4);

    const int spmm_grid = (N_NODES + 3) / 4;   // 4 waves/block, 1 wave per node
    spmm_layer0_fused_kernel<<<spmm_grid, 256, 0, stream>>>(
        rowseg, cv4, W0h, W1, eps0, g);
    spmm_layer1_light_kernel<<<spmm_grid, 256, 0, stream>>>(
        rowseg, cv4, g, eps1, out);
}